// Round 15
// baseline (105.661 us; speedup 1.0000x reference)
//
#include <hip/hip_runtime.h>

#define MU_C     0.5f
#define C_NORM_C 8.0f
#define LRELU_C  0.2f
#define NCHEB    2   // output x_3 (degree-2 poly); err ~6e-4 at measured kappa

constexpr int BB = 16;   // batch
constexpr int KK = 16;   // neighbors
constexpr int EE = 6;    // embedding dim

typedef float v4f __attribute__((ext_vector_type(4)));

// ws scalar slots: sc[0] = norm accumulator (sum deg^2 + sum w^2)
//                  sc[2] = max_n deg_n (float bits via int atomicMax)

__device__ __forceinline__ void cheb_params(const float* __restrict__ sc,
                                            float& musc, float& theta, float& delta) {
    float scale = C_NORM_C * rsqrtf(sc[0] + 1e-30f);
    musc = MU_C * scale;
    float mdeg = __int_as_float(((const int*)sc)[2]) * scale;
    float lub = 1.f + MU_C * fminf(2.f * mdeg, 8.f);
    theta = 0.5f * (lub + 1.f);
    delta = fmaxf(0.5f * (lub - 1.f), 1e-12f);
}

// Features stored as 4 batch-quad planes: ffp[bq][n][12] (bq plane = 2.4 MB,
// fits one XCD's 4 MB L2). Bt stored as 4 quad planes Btp[q][n][4].
// Block 0 zeroes the scalar slots.
__global__ void k_feat(const float* __restrict__ x,
                       const float* __restrict__ emb,
                       const float* __restrict__ fcw,
                       const float* __restrict__ fcb,
                       float* __restrict__ ffp,
                       float* __restrict__ Btp,
                       float* __restrict__ sc,
                       int N) {
    if (blockIdx.x == 0 && threadIdx.x < 64) sc[threadIdx.x] = 0.f;
    int n = blockIdx.x * blockDim.x + threadIdx.x;
    if (n >= N) return;
    float ev[EE];
#pragma unroll
    for (int j = 0; j < EE; ++j) ev[j] = emb[(size_t)n * EE + j];
    float g[3], w0[3];
#pragma unroll
    for (int f = 0; f < 3; ++f) {
        w0[f] = fcw[f * (EE + 1)];
        float s = fcb[f];
#pragma unroll
        for (int j = 0; j < EE; ++j) s += fcw[f * (EE + 1) + 1 + j] * ev[j];
        g[f] = s;
    }
    float o[BB * 3];
    float bt[BB];
#pragma unroll
    for (int b = 0; b < BB; ++b) {
        float xv = x[(size_t)b * N + n];
        bt[b] = xv;
#pragma unroll
        for (int f = 0; f < 3; ++f) {
            float v = g[f] + w0[f] * xv;
            o[b * 3 + f] = (v >= 0.f) ? v : LRELU_C * v;
        }
    }
#pragma unroll
    for (int bq = 0; bq < 4; ++bq) {
        float4* dst = (float4*)(ffp + (size_t)bq * 12 * N + (size_t)n * 12);
#pragma unroll
        for (int q = 0; q < 3; ++q) dst[q] = ((const float4*)(o + bq * 12))[q];
        *(float4*)(Btp + (size_t)bq * 4 * N + (size_t)n * 4) =
            ((const float4*)bt)[bq];
    }
}

// Similarity-weight partial sums, plane-partitioned: bq = blockIdx&3 so
// (under round-robin block->XCD dispatch) each XCD gathers within ONE
// 2.4 MB plane -> L2-resident. Thread (n,bq): 16 neighbor gathers of its
// 48B slice, sum exp over its 4 batches, write partial[bq][n][16].
// No cross-thread combination here (done in k_wsum).
__global__ void __launch_bounds__(256, 2)
k_weights(const int* __restrict__ nl,
          const float* __restrict__ ffp,
          const float* __restrict__ theta_p,
          float* __restrict__ prt,
          int N) {
    int bq = blockIdx.x & 3;
    int n = (blockIdx.x >> 2) * 256 + threadIdx.x;
    if (n >= N) return;
    const float* plane = ffp + (size_t)bq * 12 * N;
    float inv2t = 0.5f / theta_p[0];
    float fs[12];
    const float4* src = (const float4*)(plane + (size_t)n * 12);
#pragma unroll
    for (int q = 0; q < 3; ++q) ((float4*)fs)[q] = src[q];
    int idx[KK];
#pragma unroll
    for (int q = 0; q < 4; ++q)
        ((int4*)idx)[q] = ((const int4*)(nl + (size_t)n * KK))[q];
    float sum[KK];
#pragma unroll
    for (int k = 0; k < KK; ++k) {
        int nbs = idx[k] < 0 ? 0 : idx[k];
        float fn[12];
        const float4* ns = (const float4*)(plane + (size_t)nbs * 12);
#pragma unroll
        for (int q = 0; q < 3; ++q) ((float4*)fn)[q] = ns[q];
        float s = 0.f;
#pragma unroll
        for (int b = 0; b < 4; ++b) {
            float d0 = fs[b * 3 + 0] - fn[b * 3 + 0];
            float d1 = fs[b * 3 + 1] - fn[b * 3 + 1];
            float d2 = fs[b * 3 + 2] - fn[b * 3 + 2];
            s += __expf(-(d0 * d0 + d1 * d1 + d2 * d2) * inv2t);
        }
        sum[k] = s;
    }
    float4* dst = (float4*)(prt + (size_t)bq * 16 * N + (size_t)n * 16);
#pragma unroll
    for (int q = 0; q < 4; ++q) dst[q] = ((const float4*)sum)[q];
}

// Combine the 4 bq partials -> wl, plus deg / F-norm / maxdeg reductions.
// Thread = (node n, k-quad kq). Pure streaming (16 MB in, 3.2 MB out).
__global__ void k_wsum(const int* __restrict__ nl,
                       const float* __restrict__ prt,
                       float* __restrict__ wl,
                       float* __restrict__ sc,
                       int N) {
    __shared__ float ldsS[8];
    __shared__ float ldsM[8];
    int t = blockIdx.x * blockDim.x + threadIdx.x;
    int n = t >> 2, kq = t & 3;
    float tp = 0.f, dm = 0.f;
    if (n < N) {
        v4f s4 = {0.f, 0.f, 0.f, 0.f};
#pragma unroll
        for (int bq = 0; bq < 4; ++bq)
            s4 += *(const v4f*)(prt + (size_t)bq * 16 * N + (size_t)n * 16 + kq * 4);
        int4 iv = ((const int4*)(nl + (size_t)n * KK))[kq];
        v4f wk;
        wk.x = s4.x * (1.f / BB) * ((iv.x >= 0) ? 1.f : 0.f);
        wk.y = s4.y * (1.f / BB) * ((iv.y >= 0) ? 1.f : 0.f);
        wk.z = s4.z * (1.f / BB) * ((iv.z >= 0) ? 1.f : 0.f);
        wk.w = s4.w * (1.f / BB) * ((iv.w >= 0) ? 1.f : 0.f);
        *(v4f*)(wl + (size_t)n * KK + kq * 4) = wk;
        float deg = wk.x + wk.y + wk.z + wk.w;
        float sw2 = wk.x * wk.x + wk.y * wk.y + wk.z * wk.z + wk.w * wk.w;
        deg += __shfl_xor(deg, 1, 4);
        deg += __shfl_xor(deg, 2, 4);
        sw2 += __shfl_xor(sw2, 1, 4);
        sw2 += __shfl_xor(sw2, 2, 4);
        tp = (kq == 0) ? (deg * deg + sw2) : 0.f;
        dm = (kq == 0) ? deg : 0.f;
    }
#pragma unroll
    for (int off = 32; off > 0; off >>= 1) {
        tp += __shfl_down(tp, off);
        dm = fmaxf(dm, __shfl_down(dm, off));
    }
    int lane = threadIdx.x & 63, wid = threadIdx.x >> 6;
    if (lane == 0) { ldsS[wid] = tp; ldsM[wid] = dm; }
    __syncthreads();
    if (threadIdx.x == 0) {
        float ss = 0.f, sm = 0.f;
        int nw = blockDim.x >> 6;
        for (int wv = 0; wv < nw; ++wv) {
            ss += ldsS[wv];
            sm = fmaxf(sm, ldsM[wv]);
        }
        atomicAdd(sc, ss);
        atomicMax((int*)sc + 2, __float_as_int(sm));
    }
}

// Two-term Chebyshev step on plane-major state: q = blockIdx&3 so each XCD
// gathers within one 800 KB plane (L2-resident).
//   x_{k+1} = x_k + c1*(x_k - x_{k-1}) + c2*(b - A x_k)
// k==1 runs directly on Bt planes (x1 = b/theta folded via linearity);
// k==2 (==NCHEB) recomputes x_prev = bt/theta and writes out transposed.
__global__ void __launch_bounds__(256, 3)
k_cheb(const int* __restrict__ nl,
       const float* __restrict__ wl,
       const float* __restrict__ Xcur,   // plane-major: k==1 Btp, k==2 Xap
       const float* __restrict__ Btp,
       float* __restrict__ Xout,         // k==1: Xap
       const float* __restrict__ sc,
       float* __restrict__ out,
       int N, int k) {
    int q = blockIdx.x & 3;
    int n = (blockIdx.x >> 2) * 256 + threadIdx.x;
    if (n >= N) return;
    float musc, theta, delta;
    cheb_params(sc, musc, theta, delta);
    float sig1 = theta / delta;
    float rp = delta / theta;              // rho_0
    float rk = rp;
    for (int j = 1; j <= k; ++j) {
        rk = 1.f / (2.f * sig1 - rp);
        if (j < k) rp = rk;
    }
    float c1 = rk * rp;
    float c2 = 2.f * rk / delta;
    float invt = 1.f / theta;

    const float* plane = Xcur + (size_t)q * 4 * N;
    v4f ck = *(const v4f*)(plane + (size_t)n * 4);
    int idx[KK];
    float wr[KK];
#pragma unroll
    for (int qq = 0; qq < 4; ++qq) {
        int4 iv = ((const int4*)(nl + (size_t)n * KK))[qq];
        iv.x = iv.x < 0 ? 0 : iv.x;
        iv.y = iv.y < 0 ? 0 : iv.y;
        iv.z = iv.z < 0 ? 0 : iv.z;
        iv.w = iv.w < 0 ? 0 : iv.w;
        ((int4*)idx)[qq] = iv;
        ((float4*)wr)[qq] = ((const float4*)(wl + (size_t)n * KK))[qq];
    }
    v4f v[KK];
#pragma unroll
    for (int kk = 0; kk < KK; ++kk)
        v[kk] = *(const v4f*)(plane + (size_t)idx[kk] * 4);
    v4f acc = {0.f, 0.f, 0.f, 0.f};
#pragma unroll
    for (int kk = 0; kk < KK; ++kk)
        acc += (ck - v[kk]) * wr[kk];
    v4f axr = ck + acc * musc;             // A applied to raw rows

    v4f xn;
    if (k == 1) {
        // x2 = (invt*(1+c1)+c2)*b - c2*invt*(A b)
        xn = ck * (invt * (1.f + c1) + c2) - axr * (c2 * invt);
        *(v4f*)(Xout + (size_t)q * 4 * N + (size_t)n * 4) = xn;
    } else {
        v4f bt = *(const v4f*)(Btp + (size_t)q * 4 * N + (size_t)n * 4);
        v4f xp = bt * invt;
        xn = ck + (ck - xp) * c1 + (bt - axr) * c2;
        out[(size_t)(q * 4 + 0) * N + n] = xn.x;
        out[(size_t)(q * 4 + 1) * N + n] = xn.y;
        out[(size_t)(q * 4 + 2) * N + n] = xn.z;
        out[(size_t)(q * 4 + 3) * N + n] = xn.w;
    }
}

extern "C" void kernel_launch(void* const* d_in, const int* in_sizes, int n_in,
                              void* d_out, int out_size, void* d_ws, size_t ws_size,
                              hipStream_t stream) {
    const float* x   = (const float*)d_in[0];
    const int*   nl  = (const int*)d_in[1];
    const float* emb = (const float*)d_in[2];
    const float* fcw = (const float*)d_in[3];
    const float* fcb = (const float*)d_in[4];
    const float* th  = (const float*)d_in[5];
    int N = in_sizes[1] / KK;   // 50000

    // ws (floats), no aliasing (ws is ~256 MB):
    //   sc[512] | wl[16N] | ffp[48N] | prt[64N] | Btp[16N] | Xap[16N]
    float* sc  = (float*)d_ws;
    float* wl  = sc + 512;
    float* ffp = wl + (size_t)N * 16;
    float* prt = ffp + (size_t)N * 48;
    float* Btp = prt + (size_t)N * 64;
    float* Xap = Btp + (size_t)N * 16;
    float* outp = (float*)d_out;

    int G1 = (N + 255) / 256;
    int GP = ((N + 255) / 256) * 4;   // plane-partitioned grids (bq/q = blockIdx&3)
    int G4 = (N * 4 + 255) / 256;

    k_feat<<<G1, 256, 0, stream>>>(x, emb, fcw, fcb, ffp, Btp, sc, N);
    k_weights<<<GP, 256, 0, stream>>>(nl, ffp, th, prt, N);
    k_wsum<<<G4, 256, 0, stream>>>(nl, prt, wl, sc, N);
    k_cheb<<<GP, 256, 0, stream>>>(nl, wl, Btp, Btp, Xap, sc, outp, N, 1);
    k_cheb<<<GP, 256, 0, stream>>>(nl, wl, Xap, Btp, nullptr, sc, outp, N, 2);
}

// Round 16
// 69.559 us; speedup vs baseline: 1.5190x; 1.5190x over previous
//
#include <hip/hip_runtime.h>

#define MU_C     0.5f
#define C_NORM_C 8.0f
#define LRELU_C  0.2f
#define NCHEB    2   // output x_3; measured-kappa (~1.07) err ~6e-4 << 0.098

constexpr int BB = 16;   // batch
constexpr int KK = 16;   // neighbors
constexpr int EE = 6;    // embedding dim

typedef float v4f __attribute__((ext_vector_type(4)));

// ws scalar slots: sc[0] = norm accumulator (sum deg^2 + sum w^2)
//                  sc[2] = max_n deg_n (float bits via int atomicMax)

// Chebyshev interval: Gershgorin lambda <= 1 + mu*2*maxdeg_scaled, capped by
// unconditional lambda <= 1 + mu*||L||_F = 1 + mu*8; lambda_min >= 1.
__device__ __forceinline__ void cheb_params(const float* __restrict__ sc,
                                            float& musc, float& theta, float& delta) {
    float scale = C_NORM_C * rsqrtf(sc[0] + 1e-30f);
    musc = MU_C * scale;
    float mdeg = __int_as_float(((const int*)sc)[2]) * scale;
    float lub = 1.f + MU_C * fminf(2.f * mdeg, 8.f);
    theta = 0.5f * (lub + 1.f);
    delta = fmaxf(0.5f * (lub - 1.f), 1e-12f);
}

// f = LeakyReLU(W [x, emb] + b) stored (N,48) f32; also writes Bt = x^T (N,16).
// Block 0 zeroes the scalar slots.
__global__ void k_feat(const float* __restrict__ x,
                       const float* __restrict__ emb,
                       const float* __restrict__ fcw,
                       const float* __restrict__ fcb,
                       float* __restrict__ ffp,
                       float* __restrict__ Bt,
                       float* __restrict__ sc,
                       int N) {
    if (blockIdx.x == 0 && threadIdx.x < 64) sc[threadIdx.x] = 0.f;
    int n = blockIdx.x * blockDim.x + threadIdx.x;
    if (n >= N) return;
    float ev[EE];
#pragma unroll
    for (int j = 0; j < EE; ++j) ev[j] = emb[(size_t)n * EE + j];
    float g[3], w0[3];
#pragma unroll
    for (int f = 0; f < 3; ++f) {
        w0[f] = fcw[f * (EE + 1)];
        float s = fcb[f];
#pragma unroll
        for (int j = 0; j < EE; ++j) s += fcw[f * (EE + 1) + 1 + j] * ev[j];
        g[f] = s;
    }
    float o[BB * 3];
    float bt[BB];
#pragma unroll
    for (int b = 0; b < BB; ++b) {
        float xv = x[(size_t)b * N + n];
        bt[b] = xv;
#pragma unroll
        for (int f = 0; f < 3; ++f) {
            float v = g[f] + w0[f] * xv;
            o[b * 3 + f] = (v >= 0.f) ? v : LRELU_C * v;
        }
    }
    float4* dst = (float4*)(ffp + (size_t)n * 48);
#pragma unroll
    for (int q = 0; q < 12; ++q) dst[q] = ((const float4*)o)[q];
    float4* db = (float4*)(Bt + (size_t)n * 16);
#pragma unroll
    for (int q = 0; q < 4; ++q) db[q] = ((const float4*)bt)[q];
}

// Similarity weights, 4 threads per node (thread = (n, batch-quad bq)).
// The 4 lanes of a node are ADJACENT in the wave, so each neighbor-row
// gather is one contiguous ~192B 4-lane transaction (measured-best form).
// 2-stage width-4 shfl_xor combines the quads; lane bq writes its float4
// of the wl row (coalesced 64B).
__global__ void __launch_bounds__(256, 2)
k_weights(const int* __restrict__ nl,
          const float* __restrict__ ffp,
          const float* __restrict__ theta_p,
          float* __restrict__ wl,
          float* __restrict__ sc,
          int N) {
    __shared__ float ldsS[8];
    __shared__ float ldsM[8];
    int t = blockIdx.x * blockDim.x + threadIdx.x;
    int n = t >> 2, bq = t & 3;
    float tp = 0.f, dm = 0.f;
    if (n < N) {
        float inv2t = 0.5f / theta_p[0];
        float fs[12];
        const float4* src = (const float4*)(ffp + (size_t)n * 48 + bq * 12);
#pragma unroll
        for (int q = 0; q < 3; ++q) ((float4*)fs)[q] = src[q];
        int idx[KK];
#pragma unroll
        for (int q = 0; q < 4; ++q)
            ((int4*)idx)[q] = ((const int4*)(nl + (size_t)n * KK))[q];
        float sum[KK];
#pragma unroll
        for (int k = 0; k < KK; ++k) {
            int nbs = idx[k] < 0 ? 0 : idx[k];
            float fn[12];
            const float4* ns = (const float4*)(ffp + (size_t)nbs * 48 + bq * 12);
#pragma unroll
            for (int q = 0; q < 3; ++q) ((float4*)fn)[q] = ns[q];
            float s = 0.f;
#pragma unroll
            for (int b = 0; b < 4; ++b) {
                float d0 = fs[b * 3 + 0] - fn[b * 3 + 0];
                float d1 = fs[b * 3 + 1] - fn[b * 3 + 1];
                float d2 = fs[b * 3 + 2] - fn[b * 3 + 2];
                s += __expf(-(d0 * d0 + d1 * d1 + d2 * d2) * inv2t);
            }
            sum[k] = s;
        }
        // combine the 4 batch-quads (lanes of one node)
#pragma unroll
        for (int k = 0; k < KK; ++k) {
            sum[k] += __shfl_xor(sum[k], 1, 4);
            sum[k] += __shfl_xor(sum[k], 2, 4);
        }
        float deg = 0.f, sw2 = 0.f;
        float wk4[4];
#pragma unroll
        for (int k = 0; k < KK; ++k) {
            float wk = sum[k] * (1.f / BB) * ((idx[k] >= 0) ? 1.f : 0.f);
            deg += wk;
            sw2 += wk * wk;
            if ((k >> 2) == bq) wk4[k & 3] = wk;
        }
        *(float4*)(wl + (size_t)n * KK + bq * 4) =
            make_float4(wk4[0], wk4[1], wk4[2], wk4[3]);
        tp = (bq == 0) ? (deg * deg + sw2) : 0.f;
        dm = (bq == 0) ? deg : 0.f;
    }
#pragma unroll
    for (int off = 32; off > 0; off >>= 1) {
        tp += __shfl_down(tp, off);
        dm = fmaxf(dm, __shfl_down(dm, off));
    }
    int lane = threadIdx.x & 63, wid = threadIdx.x >> 6;
    if (lane == 0) { ldsS[wid] = tp; ldsM[wid] = dm; }
    __syncthreads();
    if (threadIdx.x == 0) {
        float ss = 0.f, sm = 0.f;
        int nw = blockDim.x >> 6;
        for (int wv = 0; wv < nw; ++wv) {
            ss += ldsS[wv];
            sm = fmaxf(sm, ldsM[wv]);
        }
        atomicAdd(sc, ss);
        atomicMax((int*)sc + 2, __float_as_int(sm));
    }
}

// Two-term Chebyshev step k (thread = (node n, quad q)):
//   x_{k+1} = x_k + c1*(x_k - x_{k-1}) + c2*(b - A x_k)
// k==1 runs directly on Bt (x1 = b/theta folded via linearity of A);
// k==2 recomputes x_prev = bt/theta; k==NCHEB writes out transposed.
__global__ void __launch_bounds__(256, 3)
k_cheb(const int* __restrict__ nl,
       const float* __restrict__ wl,
       const float* __restrict__ Xcur,   // k==1: Bt; else x_k buffer
       const float* __restrict__ Xprev,  // k>=3: x_{k-1} buffer
       const float* __restrict__ Bt,
       float* __restrict__ Xout,         // k<NCHEB: x_{k+1} buffer
       const float* __restrict__ sc,
       float* __restrict__ out,
       int N, int k) {
    int t = blockIdx.x * blockDim.x + threadIdx.x;
    if (t >= N * 4) return;
    int n = t >> 2, q = t & 3;
    float musc, theta, delta;
    cheb_params(sc, musc, theta, delta);
    float sig1 = theta / delta;
    float rp = delta / theta;              // rho_0
    float rk = rp;
    for (int j = 1; j <= k; ++j) {
        rk = 1.f / (2.f * sig1 - rp);
        if (j < k) rp = rk;
    }
    float c1 = rk * rp;
    float c2 = 2.f * rk / delta;
    float invt = 1.f / theta;

    size_t o = (size_t)n * 16 + q * 4;
    v4f ck = *(const v4f*)(Xcur + o);      // raw center row (bt if k==1)
    int idx[KK];
    float wr[KK];
#pragma unroll
    for (int qq = 0; qq < 4; ++qq) {
        int4 iv = ((const int4*)(nl + (size_t)n * KK))[qq];
        iv.x = iv.x < 0 ? 0 : iv.x;
        iv.y = iv.y < 0 ? 0 : iv.y;
        iv.z = iv.z < 0 ? 0 : iv.z;
        iv.w = iv.w < 0 ? 0 : iv.w;
        ((int4*)idx)[qq] = iv;
        ((float4*)wr)[qq] = ((const float4*)(wl + (size_t)n * KK))[qq];
    }
    v4f v[KK];
#pragma unroll
    for (int kk = 0; kk < KK; ++kk)
        v[kk] = *(const v4f*)(Xcur + (size_t)idx[kk] * 16 + q * 4);
    v4f acc = {0.f, 0.f, 0.f, 0.f};
#pragma unroll
    for (int kk = 0; kk < KK; ++kk)
        acc += (ck - v[kk]) * wr[kk];
    v4f axr = ck + acc * musc;             // A applied to raw rows

    v4f xn;
    if (k == 1) {
        // x2 = (invt*(1+c1)+c2)*b - c2*invt*(A b)
        v4f bt = ck;
        xn = bt * (invt * (1.f + c1) + c2) - axr * (c2 * invt);
    } else {
        v4f bt = *(const v4f*)(Bt + o);
        v4f xp = (k == 2) ? bt * invt : *(const v4f*)(Xprev + o);
        xn = ck + (ck - xp) * c1 + (bt - axr) * c2;
    }

    if (k == NCHEB) {
        out[(size_t)(q * 4 + 0) * N + n] = xn.x;
        out[(size_t)(q * 4 + 1) * N + n] = xn.y;
        out[(size_t)(q * 4 + 2) * N + n] = xn.z;
        out[(size_t)(q * 4 + 3) * N + n] = xn.w;
    } else {
        *(v4f*)(Xout + o) = xn;
    }
}

extern "C" void kernel_launch(void* const* d_in, const int* in_sizes, int n_in,
                              void* d_out, int out_size, void* d_ws, size_t ws_size,
                              hipStream_t stream) {
    const float* x   = (const float*)d_in[0];
    const int*   nl  = (const int*)d_in[1];
    const float* emb = (const float*)d_in[2];
    const float* fcw = (const float*)d_in[3];
    const float* fcb = (const float*)d_in[4];
    const float* th  = (const float*)d_in[5];
    int N = in_sizes[1] / KK;   // 50000

    // ws (floats): sc[512] | wl[16N] | region[64N]
    //   ffp = region[0,48N)  (dead after k_weights)
    //   Bt  = region[48N,64N) (written by k_feat, persistent)
    //   Xa  = region[0,16N) (aliases dead ffp)
    float* sc     = (float*)d_ws;
    float* wl     = sc + 512;
    float* region = wl + (size_t)N * 16;
    float* ffp = region;
    float* Bt  = region + (size_t)N * 48;
    float* Xa  = region;
    float* outp = (float*)d_out;

    int G1 = (N + 255) / 256;
    int G4 = (N * 4 + 255) / 256;

    k_feat<<<G1, 256, 0, stream>>>(x, emb, fcw, fcb, ffp, Bt, sc, N);
    k_weights<<<G4, 256, 0, stream>>>(nl, ffp, th, wl, sc, N);
    // step 1: on Bt -> Xa;  step 2: Xa (+Bt) -> out
    k_cheb<<<G4, 256, 0, stream>>>(nl, wl, Bt, nullptr, Bt, Xa, sc, outp, N, 1);
    k_cheb<<<G4, 256, 0, stream>>>(nl, wl, Xa, nullptr, Bt, nullptr, sc, outp, N, 2);
}

// Round 17
// 62.935 us; speedup vs baseline: 1.6789x; 1.1053x over previous
//
#include <hip/hip_runtime.h>
#include <hip/hip_fp16.h>

#define MU_C     0.5f
#define C_NORM_C 8.0f
#define LRELU_C  0.2f
#define NCHEB    2   // output x_3; measured-kappa (~1.07) err ~6e-4 << 0.098

constexpr int BB = 16;   // batch
constexpr int KK = 16;   // neighbors
constexpr int EE = 6;    // embedding dim

typedef float v4f __attribute__((ext_vector_type(4)));

// ws scalar slots: sc[0] = norm accumulator (sum deg^2 + sum w^2)
//                  sc[2] = max_n deg_n (float bits via int atomicMax)

__device__ __forceinline__ void cheb_params(const float* __restrict__ sc,
                                            float& musc, float& theta, float& delta) {
    float scale = C_NORM_C * rsqrtf(sc[0] + 1e-30f);
    musc = MU_C * scale;
    float mdeg = __int_as_float(((const int*)sc)[2]) * scale;
    float lub = 1.f + MU_C * fminf(2.f * mdeg, 8.f);
    theta = 0.5f * (lub + 1.f);
    delta = fmaxf(0.5f * (lub - 1.f), 1e-12f);
}

__device__ __forceinline__ void unpack8(uint4 u, float* f) {
    const __half2* h = (const __half2*)&u;
#pragma unroll
    for (int i = 0; i < 4; ++i) {
        float2 t = __half22float2(h[i]);
        f[2 * i] = t.x;
        f[2 * i + 1] = t.y;
    }
}

// Features stored f16, 128B per node row, layout [chunk c][bq][2 batches x
// (f0,f1,f2,pad)]: lane bq's load of chunk c sits at n*128 + c*64 + bq*16,
// so each load-instruction's 4 lanes cover one contiguous 64B line.
// Also writes Bt = x^T (N,16) f32. Block 0 zeroes the scalar slots.
__global__ void k_feat(const float* __restrict__ x,
                       const float* __restrict__ emb,
                       const float* __restrict__ fcw,
                       const float* __restrict__ fcb,
                       __half* __restrict__ ffp,
                       float* __restrict__ Bt,
                       float* __restrict__ sc,
                       int N) {
    if (blockIdx.x == 0 && threadIdx.x < 64) sc[threadIdx.x] = 0.f;
    int n = blockIdx.x * blockDim.x + threadIdx.x;
    if (n >= N) return;
    float ev[EE];
#pragma unroll
    for (int j = 0; j < EE; ++j) ev[j] = emb[(size_t)n * EE + j];
    float g[3], w0[3];
#pragma unroll
    for (int f = 0; f < 3; ++f) {
        w0[f] = fcw[f * (EE + 1)];
        float s = fcb[f];
#pragma unroll
        for (int j = 0; j < EE; ++j) s += fcw[f * (EE + 1) + 1 + j] * ev[j];
        g[f] = s;
    }
    __half hb[64];
    float bt[BB];
#pragma unroll
    for (int b = 0; b < BB; ++b) {
        float xv = x[(size_t)b * N + n];
        bt[b] = xv;
        int bq = b >> 2, c = (b >> 1) & 1, sub = b & 1;
        int base = c * 32 + bq * 8 + sub * 4;
#pragma unroll
        for (int f = 0; f < 3; ++f) {
            float v = g[f] + w0[f] * xv;
            hb[base + f] = __float2half((v >= 0.f) ? v : LRELU_C * v);
        }
        hb[base + 3] = __float2half(0.f);
    }
    uint4* dst = (uint4*)(ffp + (size_t)n * 64);
#pragma unroll
    for (int q = 0; q < 8; ++q) dst[q] = ((const uint4*)hb)[q];
    float4* db = (float4*)(Bt + (size_t)n * 16);
#pragma unroll
    for (int q = 0; q < 4; ++q) db[q] = ((const float4*)bt)[q];
}

// Similarity weights, 4 threads per node (thread = (n, batch-quad bq)),
// measured-best access shape; f16 rows shrink the gathered footprint
// 192B -> 128B per neighbor row. Unpack strictly after both loads.
__global__ void __launch_bounds__(256, 2)
k_weights(const int* __restrict__ nl,
          const __half* __restrict__ ffp,
          const float* __restrict__ theta_p,
          float* __restrict__ wl,
          float* __restrict__ sc,
          int N) {
    __shared__ float ldsS[8];
    __shared__ float ldsM[8];
    int t = blockIdx.x * blockDim.x + threadIdx.x;
    int n = t >> 2, bq = t & 3;
    float tp = 0.f, dm = 0.f;
    if (n < N) {
        float inv2t = 0.5f / theta_p[0];
        const uint4* fu = (const uint4*)ffp;      // 8 uint4 per node row
        uint4 sA = fu[(size_t)n * 8 + bq];
        uint4 sB = fu[(size_t)n * 8 + 4 + bq];
        float fs[16];
        unpack8(sA, fs);
        unpack8(sB, fs + 8);
        int idx[KK];
#pragma unroll
        for (int q = 0; q < 4; ++q)
            ((int4*)idx)[q] = ((const int4*)(nl + (size_t)n * KK))[q];
        float sum[KK];
#pragma unroll
        for (int k = 0; k < KK; ++k) {
            int nbs = idx[k] < 0 ? 0 : idx[k];
            uint4 nA = fu[(size_t)nbs * 8 + bq];
            uint4 nB = fu[(size_t)nbs * 8 + 4 + bq];
            float fn[16];
            unpack8(nA, fn);
            unpack8(nB, fn + 8);
            float s = 0.f;
#pragma unroll
            for (int b = 0; b < 4; ++b) {
                float d0 = fs[b * 4 + 0] - fn[b * 4 + 0];
                float d1 = fs[b * 4 + 1] - fn[b * 4 + 1];
                float d2 = fs[b * 4 + 2] - fn[b * 4 + 2];
                s += __expf(-(d0 * d0 + d1 * d1 + d2 * d2) * inv2t);
            }
            sum[k] = s;
        }
        // combine the 4 batch-quads (adjacent lanes of one node)
#pragma unroll
        for (int k = 0; k < KK; ++k) {
            sum[k] += __shfl_xor(sum[k], 1, 4);
            sum[k] += __shfl_xor(sum[k], 2, 4);
        }
        float deg = 0.f, sw2 = 0.f;
        float wk4[4];
#pragma unroll
        for (int k = 0; k < KK; ++k) {
            float wk = sum[k] * (1.f / BB) * ((idx[k] >= 0) ? 1.f : 0.f);
            deg += wk;
            sw2 += wk * wk;
            if ((k >> 2) == bq) wk4[k & 3] = wk;
        }
        *(float4*)(wl + (size_t)n * KK + bq * 4) =
            make_float4(wk4[0], wk4[1], wk4[2], wk4[3]);
        tp = (bq == 0) ? (deg * deg + sw2) : 0.f;
        dm = (bq == 0) ? deg : 0.f;
    }
#pragma unroll
    for (int off = 32; off > 0; off >>= 1) {
        tp += __shfl_down(tp, off);
        dm = fmaxf(dm, __shfl_down(dm, off));
    }
    int lane = threadIdx.x & 63, wid = threadIdx.x >> 6;
    if (lane == 0) { ldsS[wid] = tp; ldsM[wid] = dm; }
    __syncthreads();
    if (threadIdx.x == 0) {
        float ss = 0.f, sm = 0.f;
        int nw = blockDim.x >> 6;
        for (int wv = 0; wv < nw; ++wv) {
            ss += ldsS[wv];
            sm = fmaxf(sm, ldsM[wv]);
        }
        atomicAdd(sc, ss);
        atomicMax((int*)sc + 2, __float_as_int(sm));
    }
}

// Two-term Chebyshev step k (thread = (node n, quad q)):
//   x_{k+1} = x_k + c1*(x_k - x_{k-1}) + c2*(b - A x_k)
// k==1 runs directly on Bt (x1 = b/theta folded via linearity of A);
// k==2 recomputes x_prev = bt/theta; k==NCHEB writes out transposed.
__global__ void __launch_bounds__(256, 3)
k_cheb(const int* __restrict__ nl,
       const float* __restrict__ wl,
       const float* __restrict__ Xcur,   // k==1: Bt; else x_k buffer
       const float* __restrict__ Xprev,  // k>=3: x_{k-1} buffer
       const float* __restrict__ Bt,
       float* __restrict__ Xout,         // k<NCHEB: x_{k+1} buffer
       const float* __restrict__ sc,
       float* __restrict__ out,
       int N, int k) {
    int t = blockIdx.x * blockDim.x + threadIdx.x;
    if (t >= N * 4) return;
    int n = t >> 2, q = t & 3;
    float musc, theta, delta;
    cheb_params(sc, musc, theta, delta);
    float sig1 = theta / delta;
    float rp = delta / theta;              // rho_0
    float rk = rp;
    for (int j = 1; j <= k; ++j) {
        rk = 1.f / (2.f * sig1 - rp);
        if (j < k) rp = rk;
    }
    float c1 = rk * rp;
    float c2 = 2.f * rk / delta;
    float invt = 1.f / theta;

    size_t o = (size_t)n * 16 + q * 4;
    v4f ck = *(const v4f*)(Xcur + o);      // raw center row (bt if k==1)
    int idx[KK];
    float wr[KK];
#pragma unroll
    for (int qq = 0; qq < 4; ++qq) {
        int4 iv = ((const int4*)(nl + (size_t)n * KK))[qq];
        iv.x = iv.x < 0 ? 0 : iv.x;
        iv.y = iv.y < 0 ? 0 : iv.y;
        iv.z = iv.z < 0 ? 0 : iv.z;
        iv.w = iv.w < 0 ? 0 : iv.w;
        ((int4*)idx)[qq] = iv;
        ((float4*)wr)[qq] = ((const float4*)(wl + (size_t)n * KK))[qq];
    }
    v4f v[KK];
#pragma unroll
    for (int kk = 0; kk < KK; ++kk)
        v[kk] = *(const v4f*)(Xcur + (size_t)idx[kk] * 16 + q * 4);
    v4f acc = {0.f, 0.f, 0.f, 0.f};
#pragma unroll
    for (int kk = 0; kk < KK; ++kk)
        acc += (ck - v[kk]) * wr[kk];
    v4f axr = ck + acc * musc;             // A applied to raw rows

    v4f xn;
    if (k == 1) {
        // x2 = (invt*(1+c1)+c2)*b - c2*invt*(A b)
        v4f bt = ck;
        xn = bt * (invt * (1.f + c1) + c2) - axr * (c2 * invt);
    } else {
        v4f bt = *(const v4f*)(Bt + o);
        v4f xp = (k == 2) ? bt * invt : *(const v4f*)(Xprev + o);
        xn = ck + (ck - xp) * c1 + (bt - axr) * c2;
    }

    if (k == NCHEB) {
        out[(size_t)(q * 4 + 0) * N + n] = xn.x;
        out[(size_t)(q * 4 + 1) * N + n] = xn.y;
        out[(size_t)(q * 4 + 2) * N + n] = xn.z;
        out[(size_t)(q * 4 + 3) * N + n] = xn.w;
    } else {
        *(v4f*)(Xout + o) = xn;
    }
}

extern "C" void kernel_launch(void* const* d_in, const int* in_sizes, int n_in,
                              void* d_out, int out_size, void* d_ws, size_t ws_size,
                              hipStream_t stream) {
    const float* x   = (const float*)d_in[0];
    const int*   nl  = (const int*)d_in[1];
    const float* emb = (const float*)d_in[2];
    const float* fcw = (const float*)d_in[3];
    const float* fcb = (const float*)d_in[4];
    const float* th  = (const float*)d_in[5];
    int N = in_sizes[1] / KK;   // 50000

    // ws (floats): sc[512] | wl[16N] | region[64N]
    //   ffp (f16, 64N halves = 32N f32-equiv) = region[0,32N), dead after weights
    //   Bt  = region[48N,64N) (written by k_feat, persistent)
    //   Xa  = region[0,16N) (aliases dead ffp)
    float* sc     = (float*)d_ws;
    float* wl     = sc + 512;
    float* region = wl + (size_t)N * 16;
    __half* ffp = (__half*)region;
    float* Bt  = region + (size_t)N * 48;
    float* Xa  = region;
    float* outp = (float*)d_out;

    int G1 = (N + 255) / 256;
    int G4 = (N * 4 + 255) / 256;

    k_feat<<<G1, 256, 0, stream>>>(x, emb, fcw, fcb, ffp, Bt, sc, N);
    k_weights<<<G4, 256, 0, stream>>>(nl, ffp, th, wl, sc, N);
    // step 1: on Bt -> Xa;  step 2: Xa (+Bt) -> out
    k_cheb<<<G4, 256, 0, stream>>>(nl, wl, Bt, nullptr, Bt, Xa, sc, outp, N, 1);
    k_cheb<<<G4, 256, 0, stream>>>(nl, wl, Xa, nullptr, Bt, nullptr, sc, outp, N, 2);
}